// Round 12
// baseline (4799.361 us; speedup 1.0000x reference)
//
#include <hip/hip_runtime.h>
#include <hip/hip_bf16.h>

// ---------------------------------------------------------------------------
// K0: prep: cbt[d][j] = cb[j][d] (transpose), cnorm[j] = numpy-fp32 sum cb[j][d]^2
// (byte-identical to the R6/R10/R11 passing version)
// ---------------------------------------------------------------------------
__global__ __launch_bounds__(256) void prep_k(const float* __restrict__ cb,
                                              float* __restrict__ cbt,
                                              float* __restrict__ cnorm) {
  __shared__ float sv[256];
  int j = blockIdx.x, c = threadIdx.x;
  float v = cb[j * 256 + c];
  cbt[c * 1024 + j] = v;
  sv[c] = v;
  __syncthreads();
  if (c == 0) {
#pragma clang fp contract(off)
    float halves[2];
    for (int h = 0; h < 2; h++) {
      const float* a = sv + h * 128;
      float r[8];
      for (int k = 0; k < 8; k++) r[k] = a[k] * a[k];
      for (int i0 = 8; i0 < 128; i0 += 8)
        for (int k = 0; k < 8; k++) {
          float z = a[i0 + k];
          r[k] += z * z;
        }
      halves[h] = ((r[0] + r[1]) + (r[2] + r[3])) + ((r[4] + r[5]) + (r[6] + r[7]));
    }
    cnorm[j] = halves[0] + halves[1];
  }
}

// ---------------------------------------------------------------------------
// K1: conv1+conv2 ONLY (VQ split out). fma structure/order byte-identical to
// R11's encoder phase; z_e now goes to global ws (exact fp32 round-trip)
// instead of LDS. LDS drops 64->24.4 KB -> 3+ resident blocks/CU so the
// 2-barriers-per-ci drains overlap across blocks.
// ---------------------------------------------------------------------------
__global__ __launch_bounds__(256) void conv12_k(const float* __restrict__ x,
                                                const float* __restrict__ w1,
                                                const float* __restrict__ b1,
                                                const float* __restrict__ w2,
                                                const float* __restrict__ b2,
                                                float* __restrict__ z_e) {
  __shared__ float xt[38][40];  // x tile (fp32, zero-padded)
  __shared__ float sp[18][20];  // conv1 output tile for current ci
  __shared__ float sw[4224];    // conv2 weights: 16 grp x 16 co x 16, stride 264
  int t = threadIdx.x;
  int b = blockIdx.y;
  int oh0 = (blockIdx.x >> 3) * 8, ow0 = (blockIdx.x & 7) * 8;
  int ihb = 2 * oh0 - 1, iwb = 2 * ow0 - 1;
  int xrb = 2 * ihb - 1, xcb = 2 * iwb - 1;
  int pg16 = t & 15, cog = t >> 4;
  int py0 = (pg16 >> 2) * 2, px0 = (pg16 & 3) * 2;

  // ---- stage x tile ----
  const float* xb = x + b * 65536;
  for (int i = t; i < 1444; i += 256) {
    int r = i / 38, c = i - r * 38;
    int gr = xrb + r, gc = xcb + c;
    float v = 0.f;
    if (gr >= 0 && gr < 256 && gc >= 0 && gc < 256) v = xb[gr * 256 + gc];
    xt[r][c] = v;
  }

  float accO[16][4];
#pragma unroll
  for (int i = 0; i < 16; i++) {
    accO[i][0] = accO[i][1] = accO[i][2] = accO[i][3] = 0.f;
  }

  // ---- encoder: 16x16 two-level ci loop (identical to R11) ----
  for (int cio = 0; cio < 16; cio++) {
    float accI[16][4];
#pragma unroll
    for (int i = 0; i < 16; i++) {
      accI[i][0] = accI[i][1] = accI[i][2] = accI[i][3] = 0.f;
    }
    for (int cii = 0; cii < 16; cii++) {
      int ci = cio * 16 + cii;
      __syncthreads();
      float w1v[16];
#pragma unroll
      for (int k = 0; k < 16; k++) w1v[k] = w1[ci * 16 + k];
      float b1v = b1[ci];
      for (int i = t; i < 324; i += 256) {
        int r = i / 18, c = i - r * 18;
        int hr = ihb + r, hc = iwb + c;
        float v = 0.f;
        if (hr >= 0 && hr < 128 && hc >= 0 && hc < 128) {
          float a = b1v;
#pragma unroll
          for (int kh = 0; kh < 4; kh++)
#pragma unroll
            for (int kw = 0; kw < 4; kw++)
              a += xt[2 * r + kh][2 * c + kw] * w1v[kh * 4 + kw];
          v = fmaxf(a, 0.f);
        }
        sp[r][c] = v;
      }
      // conv2 weights for this ci: thread t stages co=t's 16 taps, b128 path
      {
        const float4* src = (const float4*)(w2 + (t * 256 + ci) * 16);
        float4* dst = (float4*)&sw[(t >> 4) * 264 + (t & 15) * 16];
        dst[0] = src[0];
        dst[1] = src[1];
        dst[2] = src[2];
        dst[3] = src[3];
      }
      __syncthreads();
      float p[6][6];
#pragma unroll
      for (int dr = 0; dr < 6; dr++)
#pragma unroll
        for (int dc = 0; dc < 6; dc++) p[dr][dc] = sp[2 * py0 + dr][2 * px0 + dc];
#pragma unroll
      for (int cc = 0; cc < 16; cc++) {
        const float* wp = &sw[cog * 264 + cc * 16];
        float4 wq0 = *(const float4*)(wp);
        float4 wq1 = *(const float4*)(wp + 4);
        float4 wq2 = *(const float4*)(wp + 8);
        float4 wq3 = *(const float4*)(wp + 12);
        float wv[16] = {wq0.x, wq0.y, wq0.z, wq0.w, wq1.x, wq1.y, wq1.z, wq1.w,
                        wq2.x, wq2.y, wq2.z, wq2.w, wq3.x, wq3.y, wq3.z, wq3.w};
#pragma unroll
        for (int dy = 0; dy < 2; dy++)
#pragma unroll
          for (int dx = 0; dx < 2; dx++) {
            float s = 0.f;
#pragma unroll
            for (int kh = 0; kh < 4; kh++)
#pragma unroll
              for (int kw = 0; kw < 4; kw++)
                s += p[2 * dy + kh][2 * dx + kw] * wv[kh * 4 + kw];
            accI[cc][dy * 2 + dx] += s;
          }
      }
    }
#pragma unroll
    for (int cc = 0; cc < 16; cc++)
#pragma unroll
      for (int e = 0; e < 4; e++) accO[cc][e] += accI[cc][e];
  }

  // ---- write z_e (fp32, exact) to global ws ----
#pragma unroll
  for (int cc = 0; cc < 16; cc++) {
    int co = cog * 16 + cc;
    float bv = b2[co];
    float* zeb = z_e + (b * 256 + co) * 4096;
#pragma unroll
    for (int dy = 0; dy < 2; dy++)
#pragma unroll
      for (int dx = 0; dx < 2; dx++) {
        int oh = oh0 + py0 + dy, ow = ow0 + px0 + dx;
        zeb[oh * 64 + ow] = fmaxf(accO[cc][dy * 2 + dx] + bv, 0.f);
      }
  }
}

// ---------------------------------------------------------------------------
// K2: VQ standalone. znorm/score/argmin/gather code byte-identical to R11's
// phases; only the ztT fill changed (coalesced global z_e loads; one z-row
// block of 64 points per workgroup). Per-point math is self-contained, so
// values/ordering — and hence the fragile argmin — are unchanged.
// ---------------------------------------------------------------------------
__global__ __launch_bounds__(256) void vq_k(const float* __restrict__ z_e,
                                            const float* __restrict__ cb,
                                            const float* __restrict__ cbt,
                                            const float* __restrict__ cnorm,
                                            float* __restrict__ zq) {
  __shared__ float ztT[256][64];
  int t = threadIdx.x;
  int b = blockIdx.y;
  int hw0 = blockIdx.x * 64;
  int lane = t & 63, pg = t >> 6, pbase = pg * 16;

  // ---- fill ztT[d][p] from z_e (coalesced: 64 lanes x contiguous hw) ----
  const float* zb = z_e + b * 1048576;
  for (int k = 0; k < 64; k++) {
    int dd = pg * 64 + k;
    ztT[dd][lane] = zb[dd * 4096 + hw0 + lane];
  }
  __syncthreads();

  // ---- znorm: numpy pairwise fp32 sum of z^2, point = lane ----
  float myzn;
  {
#pragma clang fp contract(off)
    float halves[2];
    for (int h = 0; h < 2; h++) {
      int base = h * 128;
      float r[8];
#pragma unroll
      for (int k = 0; k < 8; k++) {
        float z = ztT[base + k][lane];
        r[k] = z * z;
      }
      for (int i0 = 8; i0 < 128; i0 += 8)
#pragma unroll
        for (int k = 0; k < 8; k++) {
          float z = ztT[base + i0 + k][lane];
          r[k] += z * z;
        }
      halves[h] = ((r[0] + r[1]) + (r[2] + r[3])) + ((r[4] + r[5]) + (r[6] + r[7]));
    }
    myzn = halves[0] + halves[1];
  }
  float znp[16];
#pragma unroll
  for (int i = 0; i < 16; i++) znp[i] = __shfl(myzn, pbase + i, 64);

  // ---- VQ scores: 2 codes/lane/pass x 8 passes; fp32 absorbed formula ----
  float best[16];
  int bidx[16];
#pragma unroll
  for (int i = 0; i < 16; i++) {
    best[i] = 3.4e38f;
    bidx[i] = 0;
  }
  for (int pass = 0; pass < 8; pass++) {
    int j1 = pass * 128 + lane;
    float a1[16], a2[16];
#pragma unroll
    for (int i = 0; i < 16; i++) {
      a1[i] = 0.f;
      a2[i] = 0.f;
    }
    for (int d0 = 0; d0 < 256; d0 += 8) {
      float c1[8], c2[8];
#pragma unroll
      for (int k = 0; k < 8; k++) {
        c1[k] = cbt[(d0 + k) * 1024 + j1];
        c2[k] = cbt[(d0 + k) * 1024 + j1 + 64];
      }
#pragma unroll
      for (int i = 0; i < 16; i++) {
        int pp = pbase + i;
#pragma unroll
        for (int k = 0; k < 8; k++) {
          float z = ztT[d0 + k][pp];
          a1[i] = __builtin_fmaf(z, c1[k], a1[i]);
          a2[i] = __builtin_fmaf(z, c2[k], a2[i]);
        }
      }
    }
    float cn1 = cnorm[j1], cn2 = cnorm[j1 + 64];
    {
#pragma clang fp contract(off)
#pragma unroll
      for (int i = 0; i < 16; i++) {
        float t1 = znp[i] - 2.0f * a1[i];
        float s1 = t1 + cn1;
        if (s1 < best[i]) {
          best[i] = s1;
          bidx[i] = j1;
        }
        float t2 = znp[i] - 2.0f * a2[i];
        float s2 = t2 + cn2;
        if (s2 < best[i]) {
          best[i] = s2;
          bidx[i] = j1 + 64;
        }
      }
    }
  }
#pragma unroll
  for (int off = 1; off < 64; off <<= 1) {
#pragma unroll
    for (int i = 0; i < 16; i++) {
      float ov = __shfl_xor(best[i], off, 64);
      int oi = __shfl_xor(bidx[i], off, 64);
      if (ov < best[i] || (ov == best[i] && oi < bidx[i])) {
        best[i] = ov;
        bidx[i] = oi;
      }
    }
  }
  __syncthreads();
  int* sidx = (int*)&ztT[0][0];
  if (lane == 0) {
#pragma unroll
    for (int i = 0; i < 16; i++) sidx[pbase + i] = bidx[i];
  }
  __syncthreads();

  // ---- gather z_q: exact fp32 codebook rows (coalesced writes) ----
  int p = t & 63, c4 = t >> 6;
  int jw = sidx[p];
  float* zqb = zq + b * 1048576;
  for (int k = 0; k < 64; k++) {
    int c = c4 * 64 + k;
    zqb[c * 4096 + hw0 + p] = cb[jw * 256 + c];
  }
}

// ---------------------------------------------------------------------------
// K3: convT1 FULL BATCH, NO LDS / NO BARRIERS (proven in R10/R11). Added
// ONLY `#pragma unroll 2` on the ci loop: pure scheduling (loads of ci+1
// overlap fma of ci), per-accumulator fma order unchanged.
// ---------------------------------------------------------------------------
__global__ __launch_bounds__(256) void convt1_k(const float* __restrict__ zq,
                                                const float* __restrict__ w,
                                                const float* __restrict__ bias,
                                                float* __restrict__ d) {
  int t = threadIdx.x;
  int b = blockIdx.z;
  int co0 = blockIdx.y * 32;
  int oh0 = (blockIdx.x >> 2) * 32, ow0 = (blockIdx.x & 3) * 32;
  int wid8 = __builtin_amdgcn_readfirstlane(t >> 6) * 8;
  int lane = t & 63;
  int ty = lane >> 3, tx = lane & 7;
  int ihb = oh0 / 2 - 1, iwb = ow0 / 2 - 1;
  const float* zqb = zq + b * 1048576;

  int gr0 = ihb + 2 * ty, gc0 = iwb + 2 * tx;
  bool rok[4], cok[4];
  int roff[4], coff[4];
#pragma unroll
  for (int r = 0; r < 4; r++) {
    int gr = gr0 + r;
    rok[r] = (gr >= 0 && gr < 64);
    roff[r] = gr * 64;
  }
#pragma unroll
  for (int c = 0; c < 4; c++) {
    int gc = gc0 + c;
    cok[c] = (gc >= 0 && gc < 64);
    coff[c] = gc;
  }

  float acc[8][16];
#pragma unroll
  for (int i = 0; i < 8; i++)
#pragma unroll
    for (int e = 0; e < 16; e++) acc[i][e] = 0.f;

#pragma unroll 2
  for (int ci = 0; ci < 256; ci++) {
    const float* zc = zqb + ci * 4096;
    float p[4][4];
#pragma unroll
    for (int r = 0; r < 4; r++)
#pragma unroll
      for (int c = 0; c < 4; c++)
        p[r][c] = (rok[r] & cok[c]) ? zc[roff[r] + coff[c]] : 0.f;
#pragma unroll
    for (int cc = 0; cc < 8; cc++) {
      int co_s = co0 + wid8 + cc;  // wave-uniform -> scalar, contiguous in ci
      const float* wp = w + (ci * 256 + co_s) * 16;
      float wv[16];
#pragma unroll
      for (int k = 0; k < 16; k++) wv[k] = wp[k];
#pragma unroll
      for (int dy = 0; dy < 4; dy++) {
        int rA = ((dy + 1) >> 1) + 1, rB = rA - 1;
        int khA4 = (1 - (dy & 1)) * 4, khB4 = khA4 + 8;
#pragma unroll
        for (int dx = 0; dx < 4; dx++) {
          int cA = ((dx + 1) >> 1) + 1, cB = cA - 1;
          int kwA = 1 - (dx & 1), kwB = kwA + 2;
          float s = p[rA][cA] * wv[khA4 + kwA];
          s += p[rA][cB] * wv[khA4 + kwB];
          s += p[rB][cA] * wv[khB4 + kwA];
          s += p[rB][cB] * wv[khB4 + kwB];
          acc[cc][dy * 4 + dx] += s;
        }
      }
    }
  }
#pragma unroll
  for (int cc = 0; cc < 8; cc++) {
    int co = co0 + wid8 + cc;
    float bv = bias[co];
    float* db = d + (b * 256 + co) * 16384;
#pragma unroll
    for (int dy = 0; dy < 4; dy++)
#pragma unroll
      for (int dx = 0; dx < 4; dx++) {
        int oh = oh0 + 4 * ty + dy, ow = ow0 + 4 * tx + dx;
        db[oh * 128 + ow] = fmaxf(acc[cc][dy * 4 + dx] + bv, 0.f);
      }
  }
}

// ---------------------------------------------------------------------------
// K4: convT2 FULL BATCH: d fp32 (8,256,128,128) -> x_recon fp32 (8,1,256,256)
// ---------------------------------------------------------------------------
__global__ __launch_bounds__(256) void convt2_k(const float* __restrict__ d,
                                                const float* __restrict__ w,
                                                const float* __restrict__ bias,
                                                float* __restrict__ out) {
  int idx = blockIdx.x * 256 + threadIdx.x;  // < 524288
  int ow = idx & 255, oh = (idx >> 8) & 255, b = idx >> 16;
  int ihA = (oh + 1) >> 1, ihB = ihA - 1;
  int khA = 1 - (oh & 1), khB = khA + 2;
  int iwA = (ow + 1) >> 1, iwB = iwA - 1;
  int kwA = 1 - (ow & 1), kwB = kwA + 2;
  bool vA = ihA < 128, vB = ihB >= 0;
  bool uA = iwA < 128, uB = iwB >= 0;
  float acc = bias[0];
  const float* db = d + b * 4194304;
  for (int ci = 0; ci < 256; ci++) {
    const float* dc = db + ci * 16384;
    const float* wc = w + ci * 16;
    float s = 0.f;
    if (vA & uA) s += dc[ihA * 128 + iwA] * wc[khA * 4 + kwA];
    if (vA & uB) s += dc[ihA * 128 + iwB] * wc[khA * 4 + kwB];
    if (vB & uA) s += dc[ihB * 128 + iwA] * wc[khB * 4 + kwA];
    if (vB & uB) s += dc[ihB * 128 + iwB] * wc[khB * 4 + kwB];
    acc += s;
  }
  out[idx] = acc;
}

// ---------------------------------------------------------------------------
extern "C" void kernel_launch(void* const* d_in, const int* in_sizes, int n_in,
                              void* d_out, int out_size, void* d_ws, size_t ws_size,
                              hipStream_t stream) {
  const float* x = (const float*)d_in[0];
  const float* e1w = (const float*)d_in[1];
  const float* e1b = (const float*)d_in[2];
  const float* e2w = (const float*)d_in[3];
  const float* e2b = (const float*)d_in[4];
  const float* cb = (const float*)d_in[5];
  const float* d1w = (const float*)d_in[6];
  const float* d1b = (const float*)d_in[7];
  const float* d2w = (const float*)d_in[8];
  const float* d2b = (const float*)d_in[9];

  // ws layout (135,270,400 B total — same proven footprint as R6..R11):
  //   cbt   fp32 [0, 1048576)              codebook transpose [d][j]
  //   cnorm fp32 [1048576, 1052672)        numpy-fp32 |c_j|^2
  //   z_e   fp32 [1052672, 34607104)       encoder output (dead after vq_k)
  //   dbuf  fp32 [1052672, 135270400)      decoder intermediate (OVERLAPS z_e;
  //                                        written by convt1_k after vq_k)
  char* ws = (char*)d_ws;
  float* cbt = (float*)ws;
  float* cnorm = (float*)(ws + 1048576);
  float* z_e = (float*)(ws + 1052672);
  float* dbuf = (float*)(ws + 1052672);

  float* xrec = (float*)d_out;         // 524288 floats
  float* zq = (float*)d_out + 524288;  // 8388608 floats

  prep_k<<<1024, 256, 0, stream>>>(cb, cbt, cnorm);
  conv12_k<<<dim3(64, 8), 256, 0, stream>>>(x, e1w, e1b, e2w, e2b, z_e);
  vq_k<<<dim3(64, 8), 256, 0, stream>>>(z_e, cb, cbt, cnorm, zq);
  convt1_k<<<dim3(16, 8, 8), 256, 0, stream>>>(zq, d1w, d1b, dbuf);
  convt2_k<<<2048, 256, 0, stream>>>(dbuf, d2w, d2b, xrec);
}

// Round 13
// 3543.286 us; speedup vs baseline: 1.3545x; 1.3545x over previous
//
#include <hip/hip_runtime.h>
#include <hip/hip_bf16.h>

// ---------------------------------------------------------------------------
// K0: prep: cbt[d][j] = cb[j][d] (transpose), cnorm[j] = numpy-fp32 sum cb[j][d]^2
// (byte-identical to the R6..R12 passing version)
// ---------------------------------------------------------------------------
__global__ __launch_bounds__(256) void prep_k(const float* __restrict__ cb,
                                              float* __restrict__ cbt,
                                              float* __restrict__ cnorm) {
  __shared__ float sv[256];
  int j = blockIdx.x, c = threadIdx.x;
  float v = cb[j * 256 + c];
  cbt[c * 1024 + j] = v;
  sv[c] = v;
  __syncthreads();
  if (c == 0) {
#pragma clang fp contract(off)
    float halves[2];
    for (int h = 0; h < 2; h++) {
      const float* a = sv + h * 128;
      float r[8];
      for (int k = 0; k < 8; k++) r[k] = a[k] * a[k];
      for (int i0 = 8; i0 < 128; i0 += 8)
        for (int k = 0; k < 8; k++) {
          float z = a[i0 + k];
          r[k] += z * z;
        }
      halves[h] = ((r[0] + r[1]) + (r[2] + r[3])) + ((r[4] + r[5]) + (r[6] + r[7]));
    }
    cnorm[j] = halves[0] + halves[1];
  }
}

// ---------------------------------------------------------------------------
// K1: conv1+conv2 (byte-identical to R12's passing conv12_k).
// ---------------------------------------------------------------------------
__global__ __launch_bounds__(256) void conv12_k(const float* __restrict__ x,
                                                const float* __restrict__ w1,
                                                const float* __restrict__ b1,
                                                const float* __restrict__ w2,
                                                const float* __restrict__ b2,
                                                float* __restrict__ z_e) {
  __shared__ float xt[38][40];  // x tile (fp32, zero-padded)
  __shared__ float sp[18][20];  // conv1 output tile for current ci
  __shared__ float sw[4224];    // conv2 weights: 16 grp x 16 co x 16, stride 264
  int t = threadIdx.x;
  int b = blockIdx.y;
  int oh0 = (blockIdx.x >> 3) * 8, ow0 = (blockIdx.x & 7) * 8;
  int ihb = 2 * oh0 - 1, iwb = 2 * ow0 - 1;
  int xrb = 2 * ihb - 1, xcb = 2 * iwb - 1;
  int pg16 = t & 15, cog = t >> 4;
  int py0 = (pg16 >> 2) * 2, px0 = (pg16 & 3) * 2;

  // ---- stage x tile ----
  const float* xb = x + b * 65536;
  for (int i = t; i < 1444; i += 256) {
    int r = i / 38, c = i - r * 38;
    int gr = xrb + r, gc = xcb + c;
    float v = 0.f;
    if (gr >= 0 && gr < 256 && gc >= 0 && gc < 256) v = xb[gr * 256 + gc];
    xt[r][c] = v;
  }

  float accO[16][4];
#pragma unroll
  for (int i = 0; i < 16; i++) {
    accO[i][0] = accO[i][1] = accO[i][2] = accO[i][3] = 0.f;
  }

  // ---- encoder: 16x16 two-level ci loop ----
  for (int cio = 0; cio < 16; cio++) {
    float accI[16][4];
#pragma unroll
    for (int i = 0; i < 16; i++) {
      accI[i][0] = accI[i][1] = accI[i][2] = accI[i][3] = 0.f;
    }
    for (int cii = 0; cii < 16; cii++) {
      int ci = cio * 16 + cii;
      __syncthreads();
      float w1v[16];
#pragma unroll
      for (int k = 0; k < 16; k++) w1v[k] = w1[ci * 16 + k];
      float b1v = b1[ci];
      for (int i = t; i < 324; i += 256) {
        int r = i / 18, c = i - r * 18;
        int hr = ihb + r, hc = iwb + c;
        float v = 0.f;
        if (hr >= 0 && hr < 128 && hc >= 0 && hc < 128) {
          float a = b1v;
#pragma unroll
          for (int kh = 0; kh < 4; kh++)
#pragma unroll
            for (int kw = 0; kw < 4; kw++)
              a += xt[2 * r + kh][2 * c + kw] * w1v[kh * 4 + kw];
          v = fmaxf(a, 0.f);
        }
        sp[r][c] = v;
      }
      // conv2 weights for this ci: thread t stages co=t's 16 taps, b128 path
      {
        const float4* src = (const float4*)(w2 + (t * 256 + ci) * 16);
        float4* dst = (float4*)&sw[(t >> 4) * 264 + (t & 15) * 16];
        dst[0] = src[0];
        dst[1] = src[1];
        dst[2] = src[2];
        dst[3] = src[3];
      }
      __syncthreads();
      float p[6][6];
#pragma unroll
      for (int dr = 0; dr < 6; dr++)
#pragma unroll
        for (int dc = 0; dc < 6; dc++) p[dr][dc] = sp[2 * py0 + dr][2 * px0 + dc];
#pragma unroll
      for (int cc = 0; cc < 16; cc++) {
        const float* wp = &sw[cog * 264 + cc * 16];
        float4 wq0 = *(const float4*)(wp);
        float4 wq1 = *(const float4*)(wp + 4);
        float4 wq2 = *(const float4*)(wp + 8);
        float4 wq3 = *(const float4*)(wp + 12);
        float wv[16] = {wq0.x, wq0.y, wq0.z, wq0.w, wq1.x, wq1.y, wq1.z, wq1.w,
                        wq2.x, wq2.y, wq2.z, wq2.w, wq3.x, wq3.y, wq3.z, wq3.w};
#pragma unroll
        for (int dy = 0; dy < 2; dy++)
#pragma unroll
          for (int dx = 0; dx < 2; dx++) {
            float s = 0.f;
#pragma unroll
            for (int kh = 0; kh < 4; kh++)
#pragma unroll
              for (int kw = 0; kw < 4; kw++)
                s += p[2 * dy + kh][2 * dx + kw] * wv[kh * 4 + kw];
            accI[cc][dy * 2 + dx] += s;
          }
      }
    }
#pragma unroll
    for (int cc = 0; cc < 16; cc++)
#pragma unroll
      for (int e = 0; e < 4; e++) accO[cc][e] += accI[cc][e];
  }

  // ---- write z_e (fp32, exact) to global ws ----
#pragma unroll
  for (int cc = 0; cc < 16; cc++) {
    int co = cog * 16 + cc;
    float bv = b2[co];
    float* zeb = z_e + (b * 256 + co) * 4096;
#pragma unroll
    for (int dy = 0; dy < 2; dy++)
#pragma unroll
      for (int dx = 0; dx < 2; dx++) {
        int oh = oh0 + py0 + dy, ow = ow0 + px0 + dx;
        zeb[oh * 64 + ow] = fmaxf(accO[cc][dy * 2 + dx] + bv, 0.f);
      }
  }
}

// ---------------------------------------------------------------------------
// K2: VQ standalone (byte-identical to R12's passing vq_k).
// ---------------------------------------------------------------------------
__global__ __launch_bounds__(256) void vq_k(const float* __restrict__ z_e,
                                            const float* __restrict__ cb,
                                            const float* __restrict__ cbt,
                                            const float* __restrict__ cnorm,
                                            float* __restrict__ zq) {
  __shared__ float ztT[256][64];
  int t = threadIdx.x;
  int b = blockIdx.y;
  int hw0 = blockIdx.x * 64;
  int lane = t & 63, pg = t >> 6, pbase = pg * 16;

  // ---- fill ztT[d][p] from z_e (coalesced) ----
  const float* zb = z_e + b * 1048576;
  for (int k = 0; k < 64; k++) {
    int dd = pg * 64 + k;
    ztT[dd][lane] = zb[dd * 4096 + hw0 + lane];
  }
  __syncthreads();

  // ---- znorm: numpy pairwise fp32 sum of z^2, point = lane ----
  float myzn;
  {
#pragma clang fp contract(off)
    float halves[2];
    for (int h = 0; h < 2; h++) {
      int base = h * 128;
      float r[8];
#pragma unroll
      for (int k = 0; k < 8; k++) {
        float z = ztT[base + k][lane];
        r[k] = z * z;
      }
      for (int i0 = 8; i0 < 128; i0 += 8)
#pragma unroll
        for (int k = 0; k < 8; k++) {
          float z = ztT[base + i0 + k][lane];
          r[k] += z * z;
        }
      halves[h] = ((r[0] + r[1]) + (r[2] + r[3])) + ((r[4] + r[5]) + (r[6] + r[7]));
    }
    myzn = halves[0] + halves[1];
  }
  float znp[16];
#pragma unroll
  for (int i = 0; i < 16; i++) znp[i] = __shfl(myzn, pbase + i, 64);

  // ---- VQ scores: 2 codes/lane/pass x 8 passes; fp32 absorbed formula ----
  float best[16];
  int bidx[16];
#pragma unroll
  for (int i = 0; i < 16; i++) {
    best[i] = 3.4e38f;
    bidx[i] = 0;
  }
  for (int pass = 0; pass < 8; pass++) {
    int j1 = pass * 128 + lane;
    float a1[16], a2[16];
#pragma unroll
    for (int i = 0; i < 16; i++) {
      a1[i] = 0.f;
      a2[i] = 0.f;
    }
    for (int d0 = 0; d0 < 256; d0 += 8) {
      float c1[8], c2[8];
#pragma unroll
      for (int k = 0; k < 8; k++) {
        c1[k] = cbt[(d0 + k) * 1024 + j1];
        c2[k] = cbt[(d0 + k) * 1024 + j1 + 64];
      }
#pragma unroll
      for (int i = 0; i < 16; i++) {
        int pp = pbase + i;
#pragma unroll
        for (int k = 0; k < 8; k++) {
          float z = ztT[d0 + k][pp];
          a1[i] = __builtin_fmaf(z, c1[k], a1[i]);
          a2[i] = __builtin_fmaf(z, c2[k], a2[i]);
        }
      }
    }
    float cn1 = cnorm[j1], cn2 = cnorm[j1 + 64];
    {
#pragma clang fp contract(off)
#pragma unroll
      for (int i = 0; i < 16; i++) {
        float t1 = znp[i] - 2.0f * a1[i];
        float s1 = t1 + cn1;
        if (s1 < best[i]) {
          best[i] = s1;
          bidx[i] = j1;
        }
        float t2 = znp[i] - 2.0f * a2[i];
        float s2 = t2 + cn2;
        if (s2 < best[i]) {
          best[i] = s2;
          bidx[i] = j1 + 64;
        }
      }
    }
  }
#pragma unroll
  for (int off = 1; off < 64; off <<= 1) {
#pragma unroll
    for (int i = 0; i < 16; i++) {
      float ov = __shfl_xor(best[i], off, 64);
      int oi = __shfl_xor(bidx[i], off, 64);
      if (ov < best[i] || (ov == best[i] && oi < bidx[i])) {
        best[i] = ov;
        bidx[i] = oi;
      }
    }
  }
  __syncthreads();
  int* sidx = (int*)&ztT[0][0];
  if (lane == 0) {
#pragma unroll
    for (int i = 0; i < 16; i++) sidx[pbase + i] = bidx[i];
  }
  __syncthreads();

  // ---- gather z_q: exact fp32 codebook rows (coalesced writes) ----
  int p = t & 63, c4 = t >> 6;
  int jw = sidx[p];
  float* zqb = zq + b * 1048576;
  for (int k = 0; k < 64; k++) {
    int c = c4 * 64 + k;
    zqb[c * 4096 + hw0 + p] = cb[jw * 256 + c];
  }
}

// ---------------------------------------------------------------------------
// K3: convT1 FULL BATCH, NO LDS / NO BARRIERS — byte-identical to the R10/R11
// passing version (NO unroll pragma: unroll-2 cost VGPR 88->132, occupancy
// 19->12%, 2.3x slower. TLP is the binding resource here; keep VGPR <= 96).
// ---------------------------------------------------------------------------
__global__ __launch_bounds__(256) void convt1_k(const float* __restrict__ zq,
                                                const float* __restrict__ w,
                                                const float* __restrict__ bias,
                                                float* __restrict__ d) {
  int t = threadIdx.x;
  int b = blockIdx.z;
  int co0 = blockIdx.y * 32;
  int oh0 = (blockIdx.x >> 2) * 32, ow0 = (blockIdx.x & 3) * 32;
  int wid8 = __builtin_amdgcn_readfirstlane(t >> 6) * 8;
  int lane = t & 63;
  int ty = lane >> 3, tx = lane & 7;
  int ihb = oh0 / 2 - 1, iwb = ow0 / 2 - 1;
  const float* zqb = zq + b * 1048576;

  int gr0 = ihb + 2 * ty, gc0 = iwb + 2 * tx;
  bool rok[4], cok[4];
  int roff[4], coff[4];
#pragma unroll
  for (int r = 0; r < 4; r++) {
    int gr = gr0 + r;
    rok[r] = (gr >= 0 && gr < 64);
    roff[r] = gr * 64;
  }
#pragma unroll
  for (int c = 0; c < 4; c++) {
    int gc = gc0 + c;
    cok[c] = (gc >= 0 && gc < 64);
    coff[c] = gc;
  }

  float acc[8][16];
#pragma unroll
  for (int i = 0; i < 8; i++)
#pragma unroll
    for (int e = 0; e < 16; e++) acc[i][e] = 0.f;

  for (int ci = 0; ci < 256; ci++) {
    const float* zc = zqb + ci * 4096;
    float p[4][4];
#pragma unroll
    for (int r = 0; r < 4; r++)
#pragma unroll
      for (int c = 0; c < 4; c++)
        p[r][c] = (rok[r] & cok[c]) ? zc[roff[r] + coff[c]] : 0.f;
#pragma unroll
    for (int cc = 0; cc < 8; cc++) {
      int co_s = co0 + wid8 + cc;  // wave-uniform -> scalar, contiguous in ci
      const float* wp = w + (ci * 256 + co_s) * 16;
      float wv[16];
#pragma unroll
      for (int k = 0; k < 16; k++) wv[k] = wp[k];
#pragma unroll
      for (int dy = 0; dy < 4; dy++) {
        int rA = ((dy + 1) >> 1) + 1, rB = rA - 1;
        int khA4 = (1 - (dy & 1)) * 4, khB4 = khA4 + 8;
#pragma unroll
        for (int dx = 0; dx < 4; dx++) {
          int cA = ((dx + 1) >> 1) + 1, cB = cA - 1;
          int kwA = 1 - (dx & 1), kwB = kwA + 2;
          float s = p[rA][cA] * wv[khA4 + kwA];
          s += p[rA][cB] * wv[khA4 + kwB];
          s += p[rB][cA] * wv[khB4 + kwA];
          s += p[rB][cB] * wv[khB4 + kwB];
          acc[cc][dy * 4 + dx] += s;
        }
      }
    }
  }
#pragma unroll
  for (int cc = 0; cc < 8; cc++) {
    int co = co0 + wid8 + cc;
    float bv = bias[co];
    float* db = d + (b * 256 + co) * 16384;
#pragma unroll
    for (int dy = 0; dy < 4; dy++)
#pragma unroll
      for (int dx = 0; dx < 4; dx++) {
        int oh = oh0 + 4 * ty + dy, ow = ow0 + 4 * tx + dx;
        db[oh * 128 + ow] = fmaxf(acc[cc][dy * 4 + dx] + bv, 0.f);
      }
  }
}

// ---------------------------------------------------------------------------
// K4: convT2 FULL BATCH: d fp32 (8,256,128,128) -> x_recon fp32 (8,1,256,256)
// ---------------------------------------------------------------------------
__global__ __launch_bounds__(256) void convt2_k(const float* __restrict__ d,
                                                const float* __restrict__ w,
                                                const float* __restrict__ bias,
                                                float* __restrict__ out) {
  int idx = blockIdx.x * 256 + threadIdx.x;  // < 524288
  int ow = idx & 255, oh = (idx >> 8) & 255, b = idx >> 16;
  int ihA = (oh + 1) >> 1, ihB = ihA - 1;
  int khA = 1 - (oh & 1), khB = khA + 2;
  int iwA = (ow + 1) >> 1, iwB = iwA - 1;
  int kwA = 1 - (ow & 1), kwB = kwA + 2;
  bool vA = ihA < 128, vB = ihB >= 0;
  bool uA = iwA < 128, uB = iwB >= 0;
  float acc = bias[0];
  const float* db = d + b * 4194304;
  for (int ci = 0; ci < 256; ci++) {
    const float* dc = db + ci * 16384;
    const float* wc = w + ci * 16;
    float s = 0.f;
    if (vA & uA) s += dc[ihA * 128 + iwA] * wc[khA * 4 + kwA];
    if (vA & uB) s += dc[ihA * 128 + iwB] * wc[khA * 4 + kwB];
    if (vB & uA) s += dc[ihB * 128 + iwA] * wc[khB * 4 + kwA];
    if (vB & uB) s += dc[ihB * 128 + iwB] * wc[khB * 4 + kwB];
    acc += s;
  }
  out[idx] = acc;
}

// ---------------------------------------------------------------------------
extern "C" void kernel_launch(void* const* d_in, const int* in_sizes, int n_in,
                              void* d_out, int out_size, void* d_ws, size_t ws_size,
                              hipStream_t stream) {
  const float* x = (const float*)d_in[0];
  const float* e1w = (const float*)d_in[1];
  const float* e1b = (const float*)d_in[2];
  const float* e2w = (const float*)d_in[3];
  const float* e2b = (const float*)d_in[4];
  const float* cb = (const float*)d_in[5];
  const float* d1w = (const float*)d_in[6];
  const float* d1b = (const float*)d_in[7];
  const float* d2w = (const float*)d_in[8];
  const float* d2b = (const float*)d_in[9];

  // ws layout (135,270,400 B total — same proven footprint as R6..R12):
  //   cbt   fp32 [0, 1048576)              codebook transpose [d][j]
  //   cnorm fp32 [1048576, 1052672)        numpy-fp32 |c_j|^2
  //   z_e   fp32 [1052672, 34607104)       encoder output (dead after vq_k)
  //   dbuf  fp32 [1052672, 135270400)      decoder intermediate (OVERLAPS z_e;
  //                                        written by convt1_k after vq_k)
  char* ws = (char*)d_ws;
  float* cbt = (float*)ws;
  float* cnorm = (float*)(ws + 1048576);
  float* z_e = (float*)(ws + 1052672);
  float* dbuf = (float*)(ws + 1052672);

  float* xrec = (float*)d_out;         // 524288 floats
  float* zq = (float*)d_out + 524288;  // 8388608 floats

  prep_k<<<1024, 256, 0, stream>>>(cb, cbt, cnorm);
  conv12_k<<<dim3(64, 8), 256, 0, stream>>>(x, e1w, e1b, e2w, e2b, z_e);
  vq_k<<<dim3(64, 8), 256, 0, stream>>>(z_e, cb, cbt, cnorm, zq);
  convt1_k<<<dim3(16, 8, 8), 256, 0, stream>>>(zq, d1w, d1b, dbuf);
  convt2_k<<<2048, 256, 0, stream>>>(dbuf, d2w, d2b, xrec);
}